// Round 1
// 246.335 us; speedup vs baseline: 1.0200x; 1.0200x over previous
//
#include <hip/hip_runtime.h>

// RbfNet on MI355X — round 21:
// (a) gather MLP fix: VGPR_Count=20 proved the compiler serialized the "batched"
//     gather loads (load->wait->fma pairs, one exposed latency per edge).
//     Now: rounds 0+1 issued together (32 loads in flight, clamped), then
//     sched_barrier(0) pins the batch before the FMA loops; weights recomputed
//     from SGPR records at consume (no VGPR arrays). Applied to layer0_gemm,
//     conv_gemm, conv2_kernel. launch_bounds(...,8) keeps VGPR<=64 (8 w/SIMD).
// (b) MFMA tail: all WTul fragments (2-3 tiles) prefetched before first MFMA.
// Structure: UL[j] = [x_j @ cW (p-major, 512) | x_j @ fW (64)]; conv(x)[i] =
// sum_e w0*U[j,p] + w1*U[j,p+1]; layer3 via T[j][p] = ansc2[j] @ cW3[p].
// Edge record (4B): j(15b) | p(3b) | round(w0*16383)(14b); w1 = 1-w0.

#define CAP 48

typedef __attribute__((ext_vector_type(8))) short short8;
typedef __attribute__((ext_vector_type(4))) short short4v;
typedef __attribute__((ext_vector_type(4))) float f32x4;

__device__ __forceinline__ short bf16s(float f) {   // fp32 -> bf16 RNE
  unsigned u = __float_as_uint(f);
  return (short)((u + 0x7FFF + ((u >> 16) & 1)) >> 16);
}
__device__ __forceinline__ float b2f(unsigned short s) {
  return __uint_as_float(((unsigned)s) << 16);
}
__device__ __forceinline__ unsigned pack2(float a, float b) {
  return (unsigned)(unsigned short)bf16s(a) | ((unsigned)(unsigned short)bf16s(b) << 16);
}

// ---------- fused: edge-bucket build | WTul prep | U0L0 prep (3 block ranges) ----------
__global__ void fill_prep(const float* __restrict__ dist,
                          const int* __restrict__ fi, const int* __restrict__ fj,
                          int* __restrict__ cnt, int* __restrict__ jw, int nE,
                          const float* __restrict__ cW1, const float* __restrict__ fW1,
                          const float* __restrict__ cW2, const float* __restrict__ fW2,
                          short* __restrict__ wt1, short* __restrict__ wt2,
                          const float* __restrict__ X,    // [n,4]
                          const float* __restrict__ cW0,  // [8,4,32]
                          const float* __restrict__ fW0,  // [4,32]
                          unsigned short* __restrict__ U0, int n,
                          int fillBlocks, int prepBlocks) {
  if ((int)blockIdx.x < fillBlocks) {
    int e = blockIdx.x * blockDim.x + threadIdx.x;
    if (e >= nE) return;
    int i = fi[e], j = fj[e];
    if (i == j) return;                  // centerIgnore
    float d = fminf(1.0f, fmaxf(-1.0f, dist[e]));
    float u = (d + 1.0f) * 3.5f;         // hat centers: spacing 2/7
    int p = min((int)u, 6);
    float w0 = 1.0f - (u - (float)p);
    int wq = (int)(w0 * 16383.0f + 0.5f);
    int pos = atomicAdd(&cnt[i], 1);
    if (pos < CAP)
      jw[(size_t)i * CAP + pos] = j | (p << 15) | (wq << 18);
  } else if ((int)blockIdx.x < fillBlocks + prepBlocks) {
    int idx = ((int)blockIdx.x - fillBlocks) * blockDim.x + threadIdx.x;
    if (idx >= 2 * 576 * 64) return;
    int sel = idx / (576 * 64);
    int r = idx - sel * (576 * 64);
    int col = r >> 6, ch = r & 63;
    const float* cW = sel ? cW2 : cW1;
    const float* fW = sel ? fW2 : fW1;
    float v;
    if (col < 512) {
      int p = col >> 6, co = col & 63;
      v = cW[((size_t)p * 64 + ch) * 64 + co];
    } else {
      v = fW[(size_t)ch * 64 + (col - 512)];
    }
    (sel ? wt2 : wt1)[(size_t)col * 64 + ch] = bf16s(v);
  } else {
    // U0L0: [n,288] bf16, 4 channels/thread (groups of 4 never cross a p boundary)
    int idx = ((int)blockIdx.x - fillBlocks - prepBlocks) * blockDim.x + threadIdx.x;
    if (idx >= n * 72) return;
    int i = idx / 72, g = idx - i * 72;
    float4 x = *(const float4*)(X + (size_t)i * 4);
    float xk[4] = {x.x, x.y, x.z, x.w};
    float s[4] = {0, 0, 0, 0};
    if (g < 64) {                        // conv: p = g>>3, channels (g*4)&31 ..+3
      int p = g >> 3;
      int co = (g * 4) & 31;
      #pragma unroll
      for (int k = 0; k < 4; ++k) {
        const float* wr = cW0 + ((size_t)p * 4 + k) * 32 + co;
        #pragma unroll
        for (int c = 0; c < 4; ++c) s[c] = fmaf(xk[k], wr[c], s[c]);
      }
    } else {                             // lin: channels (g-64)*4 ..+3
      int co = (g - 64) * 4;
      #pragma unroll
      for (int k = 0; k < 4; ++k) {
        const float* wr = fW0 + (size_t)k * 32 + co;
        #pragma unroll
        for (int c = 0; c < 4; ++c) s[c] = fmaf(xk[k], wr[c], s[c]);
      }
    }
    uint2 pk = make_uint2(pack2(s[0], s[1]), pack2(s[2], s[3]));
    *(uint2*)(U0 + (size_t)i * 288 + g * 4) = pk;
  }
}

// ---- shared MFMA tail: UL[16,576] = sXa[16,64] @ WT^T; wave w does tiles w,w+16,(w+32)
__device__ __forceinline__ void gemm_tail(const unsigned short* sXa, short* sUL,
                                          const short* __restrict__ WT,
                                          int w, int lane) {
  const int mrow = lane & 15;
  const int quad = lane >> 4;
  short8 b0 = *(const short8*)(sXa + mrow * 64 + quad * 8);
  short8 b1 = *(const short8*)(sXa + mrow * 64 + quad * 8 + 32);
  const short* A0 = WT + (size_t)(w * 16 + mrow) * 64 + quad * 8;
  const short* A1 = WT + (size_t)((w + 16) * 16 + mrow) * 64 + quad * 8;
  short8 a00 = *(const short8*)(A0);
  short8 a01 = *(const short8*)(A0 + 32);
  short8 a10 = *(const short8*)(A1);
  short8 a11 = *(const short8*)(A1 + 32);
  const bool has3 = (w < 4);            // tiles 32..35 (36 total)
  short8 a20 = {0, 0, 0, 0, 0, 0, 0, 0};
  short8 a21 = {0, 0, 0, 0, 0, 0, 0, 0};
  if (has3) {
    const short* A2 = WT + (size_t)((w + 32) * 16 + mrow) * 64 + quad * 8;
    a20 = *(const short8*)(A2);
    a21 = *(const short8*)(A2 + 32);
  }
  __builtin_amdgcn_sched_barrier(0);    // all fragment loads in flight first
  f32x4 acc0 = {0, 0, 0, 0}, acc1 = {0, 0, 0, 0};
  acc0 = __builtin_amdgcn_mfma_f32_16x16x32_bf16(a00, b0, acc0, 0, 0, 0);
  acc0 = __builtin_amdgcn_mfma_f32_16x16x32_bf16(a01, b1, acc0, 0, 0, 0);
  acc1 = __builtin_amdgcn_mfma_f32_16x16x32_bf16(a10, b0, acc1, 0, 0, 0);
  acc1 = __builtin_amdgcn_mfma_f32_16x16x32_bf16(a11, b1, acc1, 0, 0, 0);
  short4v pk;
  #pragma unroll
  for (int r = 0; r < 4; ++r) pk[r] = bf16s(acc0[r]);
  *(short4v*)(sUL + mrow * 584 + w * 16 + quad * 4) = pk;
  #pragma unroll
  for (int r = 0; r < 4; ++r) pk[r] = bf16s(acc1[r]);
  *(short4v*)(sUL + mrow * 584 + (w + 16) * 16 + quad * 4) = pk;
  if (has3) {
    f32x4 acc2 = {0, 0, 0, 0};
    acc2 = __builtin_amdgcn_mfma_f32_16x16x32_bf16(a20, b0, acc2, 0, 0, 0);
    acc2 = __builtin_amdgcn_mfma_f32_16x16x32_bf16(a21, b1, acc2, 0, 0, 0);
    #pragma unroll
    for (int r = 0; r < 4; ++r) pk[r] = bf16s(acc2[r]);
    *(short4v*)(sUL + mrow * 584 + (w + 32) * 16 + quad * 4) = pk;
  }
}

// ---------- FUSED layer0 + gemm_ul1: 1024 threads, wave-per-node, no atomics ----------
__global__ __launch_bounds__(1024, 8) void layer0_gemm(
    const unsigned short* __restrict__ U0,  // [n,288] bf16 (p-major conv ++ lin)
    const int* __restrict__ cnt, const int* __restrict__ jw,
    const float* __restrict__ cb0, const float* __restrict__ fb0,
    const short* __restrict__ WTul,   // [576,64] bf16 layer-1 weights (L2-resident)
    unsigned short* __restrict__ UL, int n) {
  __shared__ __align__(16) unsigned short sXa[16 * 64];   // ansc0 tile, bf16
  __shared__ __align__(16) short sUL[16 * 584];           // UL staging
  const int tid = threadIdx.x;
  const int w = tid >> 6;                 // wave 0..15, owns node w
  const int lane = tid & 63;
  const int grp = lane >> 5;              // 0: even edges, 1: odd edges
  const int gl = lane & 31;               // uint index within the 128B span
  const int nodeBase = blockIdx.x * 16;
  const int i = nodeBase + w;
  const bool valid = (i < n);
  const int ic = valid ? i : 0;

  int rec = jw[(size_t)ic * CAP + (lane < CAP ? lane : 0)];
  const int m = valid ? min(cnt[ic], CAP) : 0;
  const int mc = m - 1;
  float accLo = 0.0f, accHi = 0.0f;
  const unsigned* __restrict__ u0W = (const unsigned*)U0;
  unsigned rA[8], rB[8];
  float wA[8], wB[8];
#define L0_LOAD(R, WS, Q0)                                                  \
  _Pragma("unroll")                                                         \
  for (int k = 0; k < 8; ++k) {                                             \
    int eA = (Q0) + 2 * k;                                                  \
    int vA = __builtin_amdgcn_readlane(rec, min(eA, mc));                   \
    int vB = __builtin_amdgcn_readlane(rec, min(eA + 1, mc));               \
    int v = grp ? vB : vA;                                                  \
    int j = v & 0x7FFF;                                                     \
    int p = (v >> 15) & 7;                                                  \
    float w0 = (float)((unsigned)v >> 18) * (1.0f / 16383.0f);              \
    float wgt = (gl < 16) ? w0 : (1.0f - w0);                               \
    WS[k] = (eA + grp < m) ? wgt : 0.0f;                                    \
    R[k] = u0W[(size_t)j * 144 + p * 16 + gl];                              \
  }
#define L0_FMA(R, WS)                                                       \
  _Pragma("unroll")                                                         \
  for (int k = 0; k < 8; ++k) {                                             \
    accLo = fmaf(WS[k], __uint_as_float(R[k] << 16), accLo);                \
    accHi = fmaf(WS[k], __uint_as_float(R[k] & 0xFFFF0000u), accHi);        \
  }
  if (m > 0) {
    L0_LOAD(rA, wA, 0);
    L0_LOAD(rB, wB, 16);                 // clamped when m<=16 (same line, L1 hit)
    __builtin_amdgcn_sched_barrier(0);   // pin: all 16 loads in flight before FMA
    L0_FMA(rA, wA);
    if (m > 16) {
      L0_FMA(rB, wB);
      for (int q0 = 32; q0 < m; q0 += 16) {   // P(m>32) ~ 1e-4: not pipelined
        L0_LOAD(rA, wA, q0);
        __builtin_amdgcn_sched_barrier(0);
        L0_FMA(rA, wA);
      }
    }
  }
#undef L0_LOAD
#undef L0_FMA
  accLo += __shfl_xor(accLo, 16, 64);     // merge u0/u1 roles
  accHi += __shfl_xor(accHi, 16, 64);
  accLo += __shfl_xor(accLo, 32, 64);     // merge even/odd edge groups
  accHi += __shfl_xor(accHi, 32, 64);
  if (lane < 16) {                        // lane l holds conv ch-pair (2l, 2l+1)
    const int l = lane;
    float c0v = fmaxf(accLo + cb0[2 * l], 0.0f);
    float c1v = fmaxf(accHi + cb0[2 * l + 1], 0.0f);
    unsigned lr = ((const unsigned*)(U0 + (size_t)ic * 288 + 256))[l];
    float l0 = fmaxf(__uint_as_float(lr << 16) + fb0[2 * l], 0.0f);
    float l1 = fmaxf(__uint_as_float(lr & 0xFFFF0000u) + fb0[2 * l + 1], 0.0f);
    unsigned* row = (unsigned*)(sXa + w * 64);
    row[l] = pack2(l0, l1);
    row[16 + l] = pack2(c0v, c1v);
  }
  __syncthreads();

  gemm_tail(sXa, sUL, WTul, w, lane);
  __syncthreads();
  const int r = tid >> 6;
  const int c0 = tid & 63;
  if (nodeBase + r < n) {
    unsigned short* dst = UL + (size_t)(nodeBase + r) * 576;
    #pragma unroll
    for (int chunk = c0; chunk < 72; chunk += 64)
      *(short8*)(dst + chunk * 8) = *(const short8*)(sUL + r * 584 + chunk * 8);
  }
}

// ---------- FUSED conv1 + gemm_ul2: 1024 threads, 16 waves = 16 nodes ----------
__global__ __launch_bounds__(1024, 8) void conv_gemm(
    const unsigned short* __restrict__ ULA, // [n,576] bf16 (layer-1 U/L)
    const int* __restrict__ cnt, const int* __restrict__ jw,
    const float* __restrict__ cb, const float* __restrict__ fb,
    const short* __restrict__ WTul2,        // [576,64] bf16 layer-2 weights
    float* __restrict__ outAns,             // ans1 fp32 [n,64] (resid for conv2)
    unsigned short* __restrict__ ULB, int n) {
  __shared__ __align__(16) unsigned short sXa[16 * 64];   // ansc1 tile, bf16
  __shared__ __align__(16) short sUL[16 * 584];           // UL2 staging
  const int tid = threadIdx.x;
  const int w = tid >> 6;
  const int lane = tid & 63;
  const int half = lane >> 5;               // 0 -> u0 (w0), 1 -> u1 (w1)
  const int pl = lane & 31;
  const int nodeBase = blockIdx.x * 16;
  const int i = nodeBase + w;
  const bool valid = (i < n);
  const int ic = valid ? i : 0;

  int rec = jw[(size_t)ic * CAP + (lane < CAP ? lane : 0)];
  const int m = valid ? min(cnt[ic], CAP) : 0;
  const int mc = m - 1;
  const unsigned Lraw = ((const unsigned*)(ULA + (size_t)ic * 576 + 512))[pl];
  float accLo = 0.0f, accHi = 0.0f;
  const unsigned* __restrict__ ulaW = (const unsigned*)ULA;
  unsigned rA[16], rB[16];
#define C1_LOAD(R, Q0)                                                      \
  _Pragma("unroll")                                                         \
  for (int k = 0; k < 16; ++k) {                                            \
    int v = __builtin_amdgcn_readlane(rec, min((Q0) + k, mc));              \
    int j = v & 0x7FFF;                                                     \
    int p = (v >> 15) & 7;                                                  \
    R[k] = ulaW[(size_t)j * 288 + p * 32 + lane];                           \
  }
#define C1_FMA(R, Q0)                                                       \
  _Pragma("unroll")                                                         \
  for (int k = 0; k < 16; ++k) {                                            \
    int v = __builtin_amdgcn_readlane(rec, min((Q0) + k, mc));              \
    float w0 = (float)((unsigned)v >> 18) * (1.0f / 16383.0f);              \
    float wv = half ? (1.0f - w0) : w0;                                     \
    wv = ((Q0) + k < m) ? wv : 0.0f;                                        \
    accLo = fmaf(wv, __uint_as_float(R[k] << 16), accLo);                   \
    accHi = fmaf(wv, __uint_as_float(R[k] & 0xFFFF0000u), accHi);           \
  }
  if (m > 0) {
    C1_LOAD(rA, 0);
    C1_LOAD(rB, 16);                     // clamped when m<=16 (same line, L1 hit)
    __builtin_amdgcn_sched_barrier(0);   // pin: 32 loads in flight before FMA
    C1_FMA(rA, 0);
    if (m > 16) {
      C1_FMA(rB, 16);
      for (int q0 = 32; q0 < m; q0 += 16) {
        C1_LOAD(rA, q0);
        __builtin_amdgcn_sched_barrier(0);
        C1_FMA(rA, q0);
      }
    }
  }
#undef C1_LOAD
#undef C1_FMA
  accLo += __shfl_xor(accLo, 32, 64);       // merge u0/u1 halves
  accHi += __shfl_xor(accHi, 32, 64);
  if (half == 0) {                          // lanes 0-31: epilogue
    unsigned* row = (unsigned*)(sXa + w * 64);
    if (valid) {
      const int c0i = 2 * pl, c1i = c0i + 1;
      float o0 = accLo + __uint_as_float(Lraw << 16) + cb[c0i] + fb[c0i];
      float o1 = accHi + __uint_as_float(Lraw & 0xFFFF0000u) + cb[c1i] + fb[c1i];
      *(float2*)(outAns + (size_t)i * 64 + c0i) = make_float2(o0, o1);
      row[pl] = pack2(fmaxf(o0, 0.0f), fmaxf(o1, 0.0f));
    } else {
      row[pl] = 0u;
    }
  }
  __syncthreads();

  gemm_tail(sXa, sUL, WTul2, w, lane);
  __syncthreads();
  const int r = tid >> 6;
  const int c0 = tid & 63;
  if (nodeBase + r < n) {
    unsigned short* dst = ULB + (size_t)(nodeBase + r) * 576;
    #pragma unroll
    for (int chunk = c0; chunk < 72; chunk += 64)
      *(short8*)(dst + chunk * 8) = *(const short8*)(sUL + r * 584 + chunk * 8);
  }
}

// ---------- conv2: wave per node; gather + resid + fused T ----------
__global__ __launch_bounds__(256, 8) void conv2_kernel(
    const unsigned short* __restrict__ UL,  // ULB [n,576] bf16
    const int* __restrict__ cnt, const int* __restrict__ jw,
    const float* __restrict__ cb, const float* __restrict__ fb,
    const float* __restrict__ resid,        // ans1 fp32 [n,64]
    const float* __restrict__ cW3,          // [8,64,2]
    float* __restrict__ T,                  // [n,16] fp32
    unsigned short* __restrict__ outAnsc, int n) {  // ansc2 bf16 [n,64]
  const int lane = threadIdx.x & 63;
  const int half = lane >> 5;
  const int pl = lane & 31;
  const int i = (blockIdx.x * blockDim.x + threadIdx.x) >> 6;
  if (i >= n) return;
  int rec = jw[(size_t)i * CAP + (lane < CAP ? lane : 0)];
  const int m = min(cnt[i], CAP);
  const int mc = m - 1;
  const unsigned Lraw = ((const unsigned*)(UL + (size_t)i * 576 + 512))[pl];
  float2 rv = *(const float2*)(resid + (size_t)i * 64 + 2 * pl);
  float accLo = 0.0f, accHi = 0.0f;
  const unsigned* __restrict__ ulW = (const unsigned*)UL;
  unsigned rA[16], rB[16];
#define C2_LOAD(R, Q0)                                                      \
  _Pragma("unroll")                                                         \
  for (int k = 0; k < 16; ++k) {                                            \
    int v = __builtin_amdgcn_readlane(rec, min((Q0) + k, mc));              \
    int j = v & 0x7FFF;                                                     \
    int p = (v >> 15) & 7;                                                  \
    R[k] = ulW[(size_t)j * 288 + p * 32 + lane];                            \
  }
#define C2_FMA(R, Q0)                                                       \
  _Pragma("unroll")                                                         \
  for (int k = 0; k < 16; ++k) {                                            \
    int v = __builtin_amdgcn_readlane(rec, min((Q0) + k, mc));              \
    float w0 = (float)((unsigned)v >> 18) * (1.0f / 16383.0f);              \
    float wv = half ? (1.0f - w0) : w0;                                     \
    wv = ((Q0) + k < m) ? wv : 0.0f;                                        \
    accLo = fmaf(wv, __uint_as_float(R[k] << 16), accLo);                   \
    accHi = fmaf(wv, __uint_as_float(R[k] & 0xFFFF0000u), accHi);           \
  }
  if (m > 0) {
    C2_LOAD(rA, 0);
    C2_LOAD(rB, 16);
    __builtin_amdgcn_sched_barrier(0);
    C2_FMA(rA, 0);
    if (m > 16) {
      C2_FMA(rB, 16);
      for (int q0 = 32; q0 < m; q0 += 16) {
        C2_LOAD(rA, q0);
        __builtin_amdgcn_sched_barrier(0);
        C2_FMA(rA, q0);
      }
    }
  }
#undef C2_LOAD
#undef C2_FMA
  accLo += __shfl_xor(accLo, 32, 64);
  accHi += __shfl_xor(accHi, 32, 64);
  if (half == 0) {
    const int c0i = 2 * pl, c1i = c0i + 1;
    float o0 = accLo + __uint_as_float(Lraw << 16) + cb[c0i] + fb[c0i] + rv.x;
    float o1 = accHi + __uint_as_float(Lraw & 0xFFFF0000u) + cb[c1i] + fb[c1i] + rv.y;
    unsigned short xb0 = (unsigned short)bf16s(fmaxf(o0, 0.0f));
    unsigned short xb1 = (unsigned short)bf16s(fmaxf(o1, 0.0f));
    ((unsigned*)(outAnsc + (size_t)i * 64))[pl] = (unsigned)xb0 | ((unsigned)xb1 << 16);
    // fused T: T[i][t] = sum_ch ansc2[i,ch] * cW3[t>>1][ch][t&1]
    float x0 = b2f(xb0), x1 = b2f(xb1);
    float c[16];
    #pragma unroll
    for (int t = 0; t < 16; ++t) {
      const float* wrow = cW3 + ((size_t)(t >> 1) * 64) * 2 + (t & 1);
      c[t] = x0 * wrow[c0i * 2] + x1 * wrow[c1i * 2];
    }
    #pragma unroll
    for (int off = 16; off > 0; off >>= 1) {
      #pragma unroll
      for (int t = 0; t < 16; ++t) c[t] += __shfl_xor(c[t], off, 64);
    }
    if (pl == 0) {
      float* tr = T + (size_t)i * 16;
      #pragma unroll
      for (int t = 0; t < 16; ++t) tr[t] = c[t];
    }
  }
}

// ---------- layer 3: wave per node, lane = edge; 16B/edge from T; + lin; reduce ----------
__global__ __launch_bounds__(256, 4) void layer3_kernel(
    const unsigned short* __restrict__ Xb,  // ansc2 [n,64] bf16
    const float* __restrict__ T,            // [n,16] fp32
    const int* __restrict__ cnt, const int* __restrict__ jw,
    const float* __restrict__ cb3, const float* __restrict__ fb3,
    const float* __restrict__ fW3,          // [64,2]
    float* __restrict__ out, int n) {
  const int lane = threadIdx.x & 63;
  const int i = (blockIdx.x * blockDim.x + threadIdx.x) >> 6;
  if (i >= n) return;
  const int m = min(cnt[i], CAP);
  float c0 = 0.0f, c1 = 0.0f;
  if (lane < m) {                      // lane = edge index (fully lane-parallel)
    int v = jw[(size_t)i * CAP + lane];
    int j = min(v & 0x7FFF, n - 1);
    int p = (v >> 15) & 7;
    float w0 = (float)((unsigned)v >> 18) * (1.0f / 16383.0f);
    float w1 = 1.0f - w0;
    const float* tb = T + (size_t)j * 16 + p * 2;
    float2 ta = *(const float2*)(tb);
    float2 tc = *(const float2*)(tb + 2);
    c0 = w0 * ta.x + w1 * tc.x;
    c1 = w0 * ta.y + w1 * tc.y;
  }
  float xi = b2f(Xb[(size_t)i * 64 + lane]);
  float2 fw = *(const float2*)(fW3 + lane * 2);
  c0 = fmaf(xi, fw.x, c0);
  c1 = fmaf(xi, fw.y, c1);
  #pragma unroll
  for (int off = 32; off > 0; off >>= 1) {
    c0 += __shfl_xor(c0, off, 64);
    c1 += __shfl_xor(c1, off, 64);
  }
  if (lane == 0) {
    out[(size_t)i * 2 + 0] = c0 + cb3[0] + fb3[0];
    out[(size_t)i * 2 + 1] = c1 + cb3[1] + fb3[1];
  }
}

extern "C" void kernel_launch(void* const* d_in, const int* in_sizes, int n_in,
                              void* d_out, int out_size, void* d_ws, size_t ws_size,
                              hipStream_t stream) {
  const float* X    = (const float*)d_in[0];
  const int*   fi   = (const int*)d_in[1];
  const int*   fj   = (const int*)d_in[2];
  const float* dist = (const float*)d_in[3];
  const float* cW0 = (const float*)d_in[4];  const float* cb0 = (const float*)d_in[5];
  const float* fW0 = (const float*)d_in[6];  const float* fb0 = (const float*)d_in[7];
  const float* cW1 = (const float*)d_in[8];  const float* cb1 = (const float*)d_in[9];
  const float* fW1 = (const float*)d_in[10]; const float* fb1 = (const float*)d_in[11];
  const float* cW2 = (const float*)d_in[12]; const float* cb2 = (const float*)d_in[13];
  const float* fW2 = (const float*)d_in[14]; const float* fb2 = (const float*)d_in[15];
  const float* cW3 = (const float*)d_in[16]; const float* cb3 = (const float*)d_in[17];
  const float* fW3 = (const float*)d_in[18]; const float* fb3 = (const float*)d_in[19];
  float* out = (float*)d_out;

  const int n  = in_sizes[0] / 4;  // N = 30000
  const int nE = in_sizes[1];      // E = 480000

  // workspace (~88.6 MB):
  //   ULA bf16[n*576] | ULB bf16[n*576] (U0[n*288] aliases its start; dead after layer0)
  // | ans1 fp32[n*64] | ansc2 bf16[n*64] | T fp32[n*16] | wt1 | wt2 | jw[n*CAP] | cnt[n]
  unsigned short* ULA   = (unsigned short*)d_ws;
  unsigned short* ULB   = ULA + (size_t)n * 576;
  unsigned short* U0    = ULB;                      // alias (dead after layer0_gemm)
  float*          ans1  = (float*)(ULB + (size_t)n * 576);
  unsigned short* ansc2 = (unsigned short*)(ans1 + (size_t)n * 64);
  float* T     = (float*)(ansc2 + (size_t)n * 64);
  short* wtul1 = (short*)(T + (size_t)n * 16);
  short* wtul2 = wtul1 + 576 * 64;
  int*   jw    = (int*)(wtul2 + 576 * 64);
  int*   cnt   = jw + (size_t)n * CAP;

  hipMemsetAsync(cnt, 0, (size_t)n * sizeof(int), stream);
  const int fillBlocks = (nE + 255) / 256;
  const int prepBlocks = (2 * 576 * 64 + 255) / 256;
  const int u0Blocks   = (n * 72 + 255) / 256;
  fill_prep<<<fillBlocks + prepBlocks + u0Blocks, 256, 0, stream>>>(
      dist, fi, fj, cnt, jw, nE, cW1, fW1, cW2, fW2, wtul1, wtul2,
      X, cW0, fW0, U0, n, fillBlocks, prepBlocks);

  // layer 0 + gemm_ul1 (reads U0=ULB region, writes ULA)
  layer0_gemm<<<(n + 15) / 16, 1024, 0, stream>>>(U0, cnt, jw, cb0, fb0,
                                                  wtul1, ULA, n);
  // conv1 + gemm_ul2 (reads ULA, writes ans1 + ULB)
  conv_gemm<<<(n + 15) / 16, 1024, 0, stream>>>(ULA, cnt, jw, cb1, fb1,
                                                wtul2, ans1, ULB, n);
  // conv2 (+resid +fused T) (reads ULB, ans1; writes ansc2, T)
  conv2_kernel<<<(n * 64 + 255) / 256, 256, 0, stream>>>(
      ULB, cnt, jw, cb2, fb2, ans1, cW3, T, ansc2, n);
  // layer 3
  layer3_kernel<<<(n * 64 + 255) / 256, 256, 0, stream>>>(ansc2, T, cnt, jw,
                                                          cb3, fb3, fW3, out, n);
}

// Round 2
// 244.035 us; speedup vs baseline: 1.0296x; 1.0094x over previous
//
#include <hip/hip_runtime.h>

// RbfNet on MI355X — round 22:
// Record rework (VALU diet): rocprof showed ~56 VALU inst/edge (VALUBusy 48% while
// HBM 28%, MfmaUtil 2%) — gather loops were VALU-issue-fat, not just latency-bound.
// (a) edge record now stores fused offset off=j*9+p (19b) | real-bit (1b) | wq (12b).
//     Gather addr = (off<<7)+lane*4 (U rows = 9 x 128B slices); layer0 = (off<<6)+gl*4;
//     layer3's T re-laid to [n,18] floats so T addr = off*8. Kills 64-bit mul chains;
//     readlane-uniform -> SALU decode + saddr loads.
// (b) weight via mantissa trick: w0 = bits(0x3F800000|wq<<11) - 1.0 (one v_sub).
// (c) jw memset to 0; pad records (v=0) decode to w0=0 AND w1=sf-w0=0 (sf=bit12),
//     so all min()/bounds clamps in the hot loops are gone; m rounds up to 16.
// Structure: UL[j] = [x_j @ cW (p-major, 512) | x_j @ fW (64)]; conv(x)[i] =
// sum_e w0*U[j,p] + w1*U[j,p+1]; layer3 via T[j][p] = ansc2[j] @ cW3[p].

#define CAP 48

typedef __attribute__((ext_vector_type(8))) short short8;
typedef __attribute__((ext_vector_type(4))) short short4v;
typedef __attribute__((ext_vector_type(4))) float f32x4;

__device__ __forceinline__ short bf16s(float f) {   // fp32 -> bf16 RNE
  unsigned u = __float_as_uint(f);
  return (short)((u + 0x7FFF + ((u >> 16) & 1)) >> 16);
}
__device__ __forceinline__ float b2f(unsigned short s) {
  return __uint_as_float(((unsigned)s) << 16);
}
__device__ __forceinline__ unsigned pack2(float a, float b) {
  return (unsigned)(unsigned short)bf16s(a) | ((unsigned)(unsigned short)bf16s(b) << 16);
}
__device__ __forceinline__ float dec_w0(int v) {    // w0 = wq * 2^-12, pad -> 0
  return __uint_as_float(0x3F800000u | (((unsigned)v & 0xFFFu) << 11)) - 1.0f;
}
__device__ __forceinline__ float dec_sf(int v) {    // 1.0 for real record, 0.0 for pad
  return (float)(((unsigned)v >> 12) & 1u);
}

// ---------- fused: edge-bucket build | WTul prep | U0L0 prep (3 block ranges) ----------
__global__ void fill_prep(const float* __restrict__ dist,
                          const int* __restrict__ fi, const int* __restrict__ fj,
                          int* __restrict__ cnt, int* __restrict__ jw, int nE,
                          const float* __restrict__ cW1, const float* __restrict__ fW1,
                          const float* __restrict__ cW2, const float* __restrict__ fW2,
                          short* __restrict__ wt1, short* __restrict__ wt2,
                          const float* __restrict__ X,    // [n,4]
                          const float* __restrict__ cW0,  // [8,4,32]
                          const float* __restrict__ fW0,  // [4,32]
                          unsigned short* __restrict__ U0, int n,
                          int fillBlocks, int prepBlocks) {
  if ((int)blockIdx.x < fillBlocks) {
    int e = blockIdx.x * blockDim.x + threadIdx.x;
    if (e >= nE) return;
    int i = fi[e], j = fj[e];
    if (i == j) return;                  // centerIgnore
    float d = fminf(1.0f, fmaxf(-1.0f, dist[e]));
    float u = (d + 1.0f) * 3.5f;         // hat centers: spacing 2/7
    int p = min((int)u, 6);
    float w0 = 1.0f - (u - (float)p);
    int wq = min((int)(w0 * 4096.0f + 0.5f), 4095);
    unsigned off = (unsigned)(j * 9 + p);          // fused table offset
    int pos = atomicAdd(&cnt[i], 1);
    if (pos < CAP)
      jw[(size_t)i * CAP + pos] = (int)((off << 13) | 0x1000u | (unsigned)wq);
  } else if ((int)blockIdx.x < fillBlocks + prepBlocks) {
    int idx = ((int)blockIdx.x - fillBlocks) * blockDim.x + threadIdx.x;
    if (idx >= 2 * 576 * 64) return;
    int sel = idx / (576 * 64);
    int r = idx - sel * (576 * 64);
    int col = r >> 6, ch = r & 63;
    const float* cW = sel ? cW2 : cW1;
    const float* fW = sel ? fW2 : fW1;
    float v;
    if (col < 512) {
      int p = col >> 6, co = col & 63;
      v = cW[((size_t)p * 64 + ch) * 64 + co];
    } else {
      v = fW[(size_t)ch * 64 + (col - 512)];
    }
    (sel ? wt2 : wt1)[(size_t)col * 64 + ch] = bf16s(v);
  } else {
    // U0L0: [n,288] bf16, 4 channels/thread (groups of 4 never cross a p boundary)
    int idx = ((int)blockIdx.x - fillBlocks - prepBlocks) * blockDim.x + threadIdx.x;
    if (idx >= n * 72) return;
    int i = idx / 72, g = idx - i * 72;
    float4 x = *(const float4*)(X + (size_t)i * 4);
    float xk[4] = {x.x, x.y, x.z, x.w};
    float s[4] = {0, 0, 0, 0};
    if (g < 64) {                        // conv: p = g>>3, channels (g*4)&31 ..+3
      int p = g >> 3;
      int co = (g * 4) & 31;
      #pragma unroll
      for (int k = 0; k < 4; ++k) {
        const float* wr = cW0 + ((size_t)p * 4 + k) * 32 + co;
        #pragma unroll
        for (int c = 0; c < 4; ++c) s[c] = fmaf(xk[k], wr[c], s[c]);
      }
    } else {                             // lin: channels (g-64)*4 ..+3
      int co = (g - 64) * 4;
      #pragma unroll
      for (int k = 0; k < 4; ++k) {
        const float* wr = fW0 + (size_t)k * 32 + co;
        #pragma unroll
        for (int c = 0; c < 4; ++c) s[c] = fmaf(xk[k], wr[c], s[c]);
      }
    }
    uint2 pk = make_uint2(pack2(s[0], s[1]), pack2(s[2], s[3]));
    *(uint2*)(U0 + (size_t)i * 288 + g * 4) = pk;
  }
}

// ---- shared MFMA tail: UL[16,576] = sXa[16,64] @ WT^T; wave w does tiles w,w+16,(w+32)
__device__ __forceinline__ void gemm_tail(const unsigned short* sXa, short* sUL,
                                          const short* __restrict__ WT,
                                          int w, int lane) {
  const int mrow = lane & 15;
  const int quad = lane >> 4;
  short8 b0 = *(const short8*)(sXa + mrow * 64 + quad * 8);
  short8 b1 = *(const short8*)(sXa + mrow * 64 + quad * 8 + 32);
  const short* A0 = WT + (size_t)(w * 16 + mrow) * 64 + quad * 8;
  const short* A1 = WT + (size_t)((w + 16) * 16 + mrow) * 64 + quad * 8;
  short8 a00 = *(const short8*)(A0);
  short8 a01 = *(const short8*)(A0 + 32);
  short8 a10 = *(const short8*)(A1);
  short8 a11 = *(const short8*)(A1 + 32);
  const bool has3 = (w < 4);            // tiles 32..35 (36 total)
  short8 a20 = {0, 0, 0, 0, 0, 0, 0, 0};
  short8 a21 = {0, 0, 0, 0, 0, 0, 0, 0};
  if (has3) {
    const short* A2 = WT + (size_t)((w + 32) * 16 + mrow) * 64 + quad * 8;
    a20 = *(const short8*)(A2);
    a21 = *(const short8*)(A2 + 32);
  }
  __builtin_amdgcn_sched_barrier(0);    // all fragment loads in flight first
  f32x4 acc0 = {0, 0, 0, 0}, acc1 = {0, 0, 0, 0};
  acc0 = __builtin_amdgcn_mfma_f32_16x16x32_bf16(a00, b0, acc0, 0, 0, 0);
  acc0 = __builtin_amdgcn_mfma_f32_16x16x32_bf16(a01, b1, acc0, 0, 0, 0);
  acc1 = __builtin_amdgcn_mfma_f32_16x16x32_bf16(a10, b0, acc1, 0, 0, 0);
  acc1 = __builtin_amdgcn_mfma_f32_16x16x32_bf16(a11, b1, acc1, 0, 0, 0);
  short4v pk;
  #pragma unroll
  for (int r = 0; r < 4; ++r) pk[r] = bf16s(acc0[r]);
  *(short4v*)(sUL + mrow * 584 + w * 16 + quad * 4) = pk;
  #pragma unroll
  for (int r = 0; r < 4; ++r) pk[r] = bf16s(acc1[r]);
  *(short4v*)(sUL + mrow * 584 + (w + 16) * 16 + quad * 4) = pk;
  if (has3) {
    f32x4 acc2 = {0, 0, 0, 0};
    acc2 = __builtin_amdgcn_mfma_f32_16x16x32_bf16(a20, b0, acc2, 0, 0, 0);
    acc2 = __builtin_amdgcn_mfma_f32_16x16x32_bf16(a21, b1, acc2, 0, 0, 0);
    #pragma unroll
    for (int r = 0; r < 4; ++r) pk[r] = bf16s(acc2[r]);
    *(short4v*)(sUL + mrow * 584 + (w + 32) * 16 + quad * 4) = pk;
  }
}

// ---------- FUSED layer0 + gemm_ul1: 1024 threads, wave-per-node, no atomics ----------
__global__ __launch_bounds__(1024, 8) void layer0_gemm(
    const unsigned short* __restrict__ U0,  // [n,288] bf16 (p-major conv ++ lin)
    const int* __restrict__ cnt, const int* __restrict__ jw,
    const float* __restrict__ cb0, const float* __restrict__ fb0,
    const short* __restrict__ WTul,   // [576,64] bf16 layer-1 weights (L2-resident)
    unsigned short* __restrict__ UL, int n) {
  __shared__ __align__(16) unsigned short sXa[16 * 64];   // ansc0 tile, bf16
  __shared__ __align__(16) short sUL[16 * 584];           // UL staging
  const int tid = threadIdx.x;
  const int w = tid >> 6;                 // wave 0..15, owns node w
  const int lane = tid & 63;
  const int grp = lane >> 5;              // 0: even edges, 1: odd edges
  const int gl = lane & 31;               // uint index within the 128B span
  const unsigned gl4 = (unsigned)gl * 4u;
  const int nodeBase = blockIdx.x * 16;
  const int i = nodeBase + w;
  const bool valid = (i < n);
  const int ic = valid ? i : 0;
  const char* __restrict__ u0B = (const char*)U0;

  int rec = jw[(size_t)ic * CAP + (lane < CAP ? lane : 0)];
  const int m = valid ? min(cnt[ic], CAP) : 0;
  float accLo = 0.0f, accHi = 0.0f;
  unsigned rA[8], rB[8];
  float wA[8], wB[8];
#define L0_LOAD(R, WS, Q0)                                                  \
  _Pragma("unroll")                                                         \
  for (int k = 0; k < 8; ++k) {                                             \
    int vA = __builtin_amdgcn_readlane(rec, (Q0) + 2 * k);                  \
    int vB = __builtin_amdgcn_readlane(rec, (Q0) + 2 * k + 1);              \
    int v = grp ? vB : vA;                                                  \
    unsigned voff = (((unsigned)v >> 7) & 0xFFFFFFC0u) + gl4;               \
    R[k] = *(const unsigned*)(u0B + voff);                                  \
    float w0 = dec_w0(v);                                                   \
    WS[k] = (gl < 16) ? w0 : (dec_sf(v) - w0);                              \
  }
#define L0_FMA(R, WS)                                                       \
  _Pragma("unroll")                                                         \
  for (int k = 0; k < 8; ++k) {                                             \
    accLo = fmaf(WS[k], __uint_as_float(R[k] << 16), accLo);                \
    accHi = fmaf(WS[k], __uint_as_float(R[k] & 0xFFFF0000u), accHi);        \
  }
  if (m > 0) {
    L0_LOAD(rA, wA, 0);
    L0_LOAD(rB, wB, 16);                 // pads beyond m decode to weight 0
    __builtin_amdgcn_sched_barrier(0);   // pin: all 16 loads in flight before FMA
    L0_FMA(rA, wA);
    if (m > 16) {
      L0_FMA(rB, wB);
      for (int q0 = 32; q0 < m; q0 += 16) {   // P(m>32) ~ 1e-4: not pipelined
        L0_LOAD(rA, wA, q0);
        __builtin_amdgcn_sched_barrier(0);
        L0_FMA(rA, wA);
      }
    }
  }
#undef L0_LOAD
#undef L0_FMA
  accLo += __shfl_xor(accLo, 16, 64);     // merge u0/u1 roles
  accHi += __shfl_xor(accHi, 16, 64);
  accLo += __shfl_xor(accLo, 32, 64);     // merge even/odd edge groups
  accHi += __shfl_xor(accHi, 32, 64);
  if (lane < 16) {                        // lane l holds conv ch-pair (2l, 2l+1)
    const int l = lane;
    float c0v = fmaxf(accLo + cb0[2 * l], 0.0f);
    float c1v = fmaxf(accHi + cb0[2 * l + 1], 0.0f);
    unsigned lr = ((const unsigned*)(U0 + (size_t)ic * 288 + 256))[l];
    float l0 = fmaxf(__uint_as_float(lr << 16) + fb0[2 * l], 0.0f);
    float l1 = fmaxf(__uint_as_float(lr & 0xFFFF0000u) + fb0[2 * l + 1], 0.0f);
    unsigned* row = (unsigned*)(sXa + w * 64);
    row[l] = pack2(l0, l1);
    row[16 + l] = pack2(c0v, c1v);
  }
  __syncthreads();

  gemm_tail(sXa, sUL, WTul, w, lane);
  __syncthreads();
  const int r = tid >> 6;
  const int c0 = tid & 63;
  if (nodeBase + r < n) {
    unsigned short* dst = UL + (size_t)(nodeBase + r) * 576;
    #pragma unroll
    for (int chunk = c0; chunk < 72; chunk += 64)
      *(short8*)(dst + chunk * 8) = *(const short8*)(sUL + r * 584 + chunk * 8);
  }
}

// ---------- FUSED conv1 + gemm_ul2: 1024 threads, 16 waves = 16 nodes ----------
__global__ __launch_bounds__(1024, 8) void conv_gemm(
    const unsigned short* __restrict__ ULA, // [n,576] bf16 (layer-1 U/L)
    const int* __restrict__ cnt, const int* __restrict__ jw,
    const float* __restrict__ cb, const float* __restrict__ fb,
    const short* __restrict__ WTul2,        // [576,64] bf16 layer-2 weights
    float* __restrict__ outAns,             // ans1 fp32 [n,64] (resid for conv2)
    unsigned short* __restrict__ ULB, int n) {
  __shared__ __align__(16) unsigned short sXa[16 * 64];   // ansc1 tile, bf16
  __shared__ __align__(16) short sUL[16 * 584];           // UL2 staging
  const int tid = threadIdx.x;
  const int w = tid >> 6;
  const int lane = tid & 63;
  const int half = lane >> 5;               // 0 -> u0 (w0), 1 -> u1 (w1)
  const int pl = lane & 31;
  const unsigned lane4 = (unsigned)lane * 4u;
  const int nodeBase = blockIdx.x * 16;
  const int i = nodeBase + w;
  const bool valid = (i < n);
  const int ic = valid ? i : 0;
  const char* __restrict__ ulB = (const char*)ULA;

  int rec = jw[(size_t)ic * CAP + (lane < CAP ? lane : 0)];
  const int m = valid ? min(cnt[ic], CAP) : 0;
  const unsigned Lraw = ((const unsigned*)(ULA + (size_t)ic * 576 + 512))[pl];
  float accLo = 0.0f, accHi = 0.0f;
  unsigned rA[16], rB[16];
#define C1_LOAD(R, Q0)                                                     \
  _Pragma("unroll")                                                        \
  for (int k = 0; k < 16; ++k) {                                           \
    int v = __builtin_amdgcn_readlane(rec, (Q0) + k);                      \
    unsigned voff = (((unsigned)v >> 6) & 0xFFFFFF80u) + lane4;            \
    R[k] = *(const unsigned*)(ulB + voff);                                 \
  }
#define C1_FMA(R, Q0)                                                      \
  _Pragma("unroll")                                                        \
  for (int k = 0; k < 16; ++k) {                                           \
    int v = __builtin_amdgcn_readlane(rec, (Q0) + k);                      \
    float w0 = dec_w0(v);                                                  \
    float wv = half ? (dec_sf(v) - w0) : w0;                               \
    accLo = fmaf(wv, __uint_as_float(R[k] << 16), accLo);                  \
    accHi = fmaf(wv, __uint_as_float(R[k] & 0xFFFF0000u), accHi);          \
  }
  if (m > 0) {
    C1_LOAD(rA, 0);
    C1_LOAD(rB, 16);                     // pads decode to weight 0
    __builtin_amdgcn_sched_barrier(0);   // pin: 32 loads in flight before FMA
    C1_FMA(rA, 0);
    if (m > 16) {
      C1_FMA(rB, 16);
      for (int q0 = 32; q0 < m; q0 += 16) {
        C1_LOAD(rA, q0);
        __builtin_amdgcn_sched_barrier(0);
        C1_FMA(rA, q0);
      }
    }
  }
#undef C1_LOAD
#undef C1_FMA
  accLo += __shfl_xor(accLo, 32, 64);       // merge u0/u1 halves
  accHi += __shfl_xor(accHi, 32, 64);
  if (half == 0) {                          // lanes 0-31: epilogue
    unsigned* row = (unsigned*)(sXa + w * 64);
    if (valid) {
      const int c0i = 2 * pl, c1i = c0i + 1;
      float o0 = accLo + __uint_as_float(Lraw << 16) + cb[c0i] + fb[c0i];
      float o1 = accHi + __uint_as_float(Lraw & 0xFFFF0000u) + cb[c1i] + fb[c1i];
      *(float2*)(outAns + (size_t)i * 64 + c0i) = make_float2(o0, o1);
      row[pl] = pack2(fmaxf(o0, 0.0f), fmaxf(o1, 0.0f));
    } else {
      row[pl] = 0u;
    }
  }
  __syncthreads();

  gemm_tail(sXa, sUL, WTul2, w, lane);
  __syncthreads();
  const int r = tid >> 6;
  const int c0 = tid & 63;
  if (nodeBase + r < n) {
    unsigned short* dst = ULB + (size_t)(nodeBase + r) * 576;
    #pragma unroll
    for (int chunk = c0; chunk < 72; chunk += 64)
      *(short8*)(dst + chunk * 8) = *(const short8*)(sUL + r * 584 + chunk * 8);
  }
}

// ---------- conv2: wave per node; gather + resid + fused T ----------
__global__ __launch_bounds__(256, 8) void conv2_kernel(
    const unsigned short* __restrict__ UL,  // ULB [n,576] bf16
    const int* __restrict__ cnt, const int* __restrict__ jw,
    const float* __restrict__ cb, const float* __restrict__ fb,
    const float* __restrict__ resid,        // ans1 fp32 [n,64]
    const float* __restrict__ cW3,          // [8,64,2]
    float* __restrict__ T,                  // [n,18] fp32 (slot p at offset p*2)
    unsigned short* __restrict__ outAnsc, int n) {  // ansc2 bf16 [n,64]
  const int lane = threadIdx.x & 63;
  const int half = lane >> 5;
  const int pl = lane & 31;
  const unsigned lane4 = (unsigned)lane * 4u;
  const int i = (blockIdx.x * blockDim.x + threadIdx.x) >> 6;
  if (i >= n) return;
  const char* __restrict__ ulB = (const char*)UL;
  int rec = jw[(size_t)i * CAP + (lane < CAP ? lane : 0)];
  const int m = min(cnt[i], CAP);
  const unsigned Lraw = ((const unsigned*)(UL + (size_t)i * 576 + 512))[pl];
  float2 rv = *(const float2*)(resid + (size_t)i * 64 + 2 * pl);
  float accLo = 0.0f, accHi = 0.0f;
  unsigned rA[16], rB[16];
#define C2_LOAD(R, Q0)                                                     \
  _Pragma("unroll")                                                        \
  for (int k = 0; k < 16; ++k) {                                           \
    int v = __builtin_amdgcn_readlane(rec, (Q0) + k);                      \
    unsigned voff = (((unsigned)v >> 6) & 0xFFFFFF80u) + lane4;            \
    R[k] = *(const unsigned*)(ulB + voff);                                 \
  }
#define C2_FMA(R, Q0)                                                      \
  _Pragma("unroll")                                                        \
  for (int k = 0; k < 16; ++k) {                                           \
    int v = __builtin_amdgcn_readlane(rec, (Q0) + k);                      \
    float w0 = dec_w0(v);                                                  \
    float wv = half ? (dec_sf(v) - w0) : w0;                               \
    accLo = fmaf(wv, __uint_as_float(R[k] << 16), accLo);                  \
    accHi = fmaf(wv, __uint_as_float(R[k] & 0xFFFF0000u), accHi);          \
  }
  if (m > 0) {
    C2_LOAD(rA, 0);
    C2_LOAD(rB, 16);
    __builtin_amdgcn_sched_barrier(0);
    C2_FMA(rA, 0);
    if (m > 16) {
      C2_FMA(rB, 16);
      for (int q0 = 32; q0 < m; q0 += 16) {
        C2_LOAD(rA, q0);
        __builtin_amdgcn_sched_barrier(0);
        C2_FMA(rA, q0);
      }
    }
  }
#undef C2_LOAD
#undef C2_FMA
  accLo += __shfl_xor(accLo, 32, 64);
  accHi += __shfl_xor(accHi, 32, 64);
  if (half == 0) {
    const int c0i = 2 * pl, c1i = c0i + 1;
    float o0 = accLo + __uint_as_float(Lraw << 16) + cb[c0i] + fb[c0i] + rv.x;
    float o1 = accHi + __uint_as_float(Lraw & 0xFFFF0000u) + cb[c1i] + fb[c1i] + rv.y;
    unsigned short xb0 = (unsigned short)bf16s(fmaxf(o0, 0.0f));
    unsigned short xb1 = (unsigned short)bf16s(fmaxf(o1, 0.0f));
    ((unsigned*)(outAnsc + (size_t)i * 64))[pl] = (unsigned)xb0 | ((unsigned)xb1 << 16);
    // fused T: T[i][t] = sum_ch ansc2[i,ch] * cW3[t>>1][ch][t&1]
    float x0 = b2f(xb0), x1 = b2f(xb1);
    float c[16];
    #pragma unroll
    for (int t = 0; t < 16; ++t) {
      const float* wrow = cW3 + ((size_t)(t >> 1) * 64) * 2 + (t & 1);
      c[t] = x0 * wrow[c0i * 2] + x1 * wrow[c1i * 2];
    }
    #pragma unroll
    for (int off = 16; off > 0; off >>= 1) {
      #pragma unroll
      for (int t = 0; t < 16; ++t) c[t] += __shfl_xor(c[t], off, 64);
    }
    if (pl == 0) {
      float* tr = T + (size_t)i * 18;     // row stride 18: slot p lives at p*2
      #pragma unroll
      for (int t = 0; t < 16; ++t) tr[t] = c[t];
    }
  }
}

// ---------- layer 3: wave per node, lane = edge; 16B/edge from T; + lin; reduce ----------
__global__ __launch_bounds__(256, 4) void layer3_kernel(
    const unsigned short* __restrict__ Xb,  // ansc2 [n,64] bf16
    const float* __restrict__ T,            // [n,18] fp32
    const int* __restrict__ cnt, const int* __restrict__ jw,
    const float* __restrict__ cb3, const float* __restrict__ fb3,
    const float* __restrict__ fW3,          // [64,2]
    float* __restrict__ out, int n) {
  const int lane = threadIdx.x & 63;
  const int i = (blockIdx.x * blockDim.x + threadIdx.x) >> 6;
  if (i >= n) return;
  const int m = min(cnt[i], CAP);
  float c0 = 0.0f, c1 = 0.0f;
  if (lane < m) {                      // lane = edge index (real records only)
    int v = jw[(size_t)i * CAP + lane];
    unsigned off = (unsigned)v >> 13;  // = j*9 + p; T row = 18 floats = 9 x 8B slots
    float w0 = dec_w0(v);
    float w1 = 1.0f - w0;
    const float* tb = T + (size_t)off * 2;
    float2 ta = *(const float2*)(tb);
    float2 tc = *(const float2*)(tb + 2);
    c0 = w0 * ta.x + w1 * tc.x;
    c1 = w0 * ta.y + w1 * tc.y;
  }
  float xi = b2f(Xb[(size_t)i * 64 + lane]);
  float2 fw = *(const float2*)(fW3 + lane * 2);
  c0 = fmaf(xi, fw.x, c0);
  c1 = fmaf(xi, fw.y, c1);
  #pragma unroll
  for (int off = 32; off > 0; off >>= 1) {
    c0 += __shfl_xor(c0, off, 64);
    c1 += __shfl_xor(c1, off, 64);
  }
  if (lane == 0) {
    out[(size_t)i * 2 + 0] = c0 + cb3[0] + fb3[0];
    out[(size_t)i * 2 + 1] = c1 + cb3[1] + fb3[1];
  }
}

extern "C" void kernel_launch(void* const* d_in, const int* in_sizes, int n_in,
                              void* d_out, int out_size, void* d_ws, size_t ws_size,
                              hipStream_t stream) {
  const float* X    = (const float*)d_in[0];
  const int*   fi   = (const int*)d_in[1];
  const int*   fj   = (const int*)d_in[2];
  const float* dist = (const float*)d_in[3];
  const float* cW0 = (const float*)d_in[4];  const float* cb0 = (const float*)d_in[5];
  const float* fW0 = (const float*)d_in[6];  const float* fb0 = (const float*)d_in[7];
  const float* cW1 = (const float*)d_in[8];  const float* cb1 = (const float*)d_in[9];
  const float* fW1 = (const float*)d_in[10]; const float* fb1 = (const float*)d_in[11];
  const float* cW2 = (const float*)d_in[12]; const float* cb2 = (const float*)d_in[13];
  const float* fW2 = (const float*)d_in[14]; const float* fb2 = (const float*)d_in[15];
  const float* cW3 = (const float*)d_in[16]; const float* cb3 = (const float*)d_in[17];
  const float* fW3 = (const float*)d_in[18]; const float* fb3 = (const float*)d_in[19];
  float* out = (float*)d_out;

  const int n  = in_sizes[0] / 4;  // N = 30000
  const int nE = in_sizes[1];      // E = 480000

  // workspace (~88.9 MB):
  //   ULA bf16[n*576] | ULB bf16[n*576] (U0[n*288] aliases its start; dead after layer0)
  // | ans1 fp32[n*64] | ansc2 bf16[n*64] | T fp32[n*18] | wt1 | wt2 | jw[n*CAP] | cnt[n]
  unsigned short* ULA   = (unsigned short*)d_ws;
  unsigned short* ULB   = ULA + (size_t)n * 576;
  unsigned short* U0    = ULB;                      // alias (dead after layer0_gemm)
  float*          ans1  = (float*)(ULB + (size_t)n * 576);
  unsigned short* ansc2 = (unsigned short*)(ans1 + (size_t)n * 64);
  float* T     = (float*)(ansc2 + (size_t)n * 64);
  short* wtul1 = (short*)(T + (size_t)n * 18);
  short* wtul2 = wtul1 + 576 * 64;
  int*   jw    = (int*)(wtul2 + 576 * 64);
  int*   cnt   = jw + (size_t)n * CAP;

  // zero jw (pad records) AND cnt in one contiguous memset
  hipMemsetAsync(jw, 0, ((size_t)n * CAP + n) * sizeof(int), stream);
  const int fillBlocks = (nE + 255) / 256;
  const int prepBlocks = (2 * 576 * 64 + 255) / 256;
  const int u0Blocks   = (n * 72 + 255) / 256;
  fill_prep<<<fillBlocks + prepBlocks + u0Blocks, 256, 0, stream>>>(
      dist, fi, fj, cnt, jw, nE, cW1, fW1, cW2, fW2, wtul1, wtul2,
      X, cW0, fW0, U0, n, fillBlocks, prepBlocks);

  // layer 0 + gemm_ul1 (reads U0=ULB region, writes ULA)
  layer0_gemm<<<(n + 15) / 16, 1024, 0, stream>>>(U0, cnt, jw, cb0, fb0,
                                                  wtul1, ULA, n);
  // conv1 + gemm_ul2 (reads ULA, writes ans1 + ULB)
  conv_gemm<<<(n + 15) / 16, 1024, 0, stream>>>(ULA, cnt, jw, cb1, fb1,
                                                wtul2, ans1, ULB, n);
  // conv2 (+resid +fused T) (reads ULB, ans1; writes ansc2, T)
  conv2_kernel<<<(n * 64 + 255) / 256, 256, 0, stream>>>(
      ULB, cnt, jw, cb2, fb2, ans1, cW3, T, ansc2, n);
  // layer 3
  layer3_kernel<<<(n * 64 + 255) / 256, 256, 0, stream>>>(ansc2, T, cnt, jw,
                                                          cb3, fb3, fW3, out, n);
}